// Round 10
// baseline (508.708 us; speedup 1.0000x reference)
//
#include <hip/hip_runtime.h>
#include <cmath>

#define B_SZ   8
#define H_DIM  5120
#define NHEAD  128
#define QLR_D  1536
#define ROPE_D 64
#define KVLR_D 512
#define KVLEN  8192
#define SCALE_F 0.07216878364870322f  // 192^-0.5

typedef _Float16 f16x8 __attribute__((ext_vector_type(8)));
typedef _Float16 f16x4 __attribute__((ext_vector_type(4)));
typedef _Float16 f16x2 __attribute__((ext_vector_type(2)));
typedef __attribute__((ext_vector_type(4))) float f32x4;

// ws layout (float offsets)
#define WS_CQY    ((size_t)0)          // 12288
#define WS_SSP    ((size_t)12288)      // 64
#define WS_CQ     ((size_t)12352)      // 12288
#define WS_TRIG   ((size_t)24640)      // 524288 (8192*32 float2)
#define WS_QH     ((size_t)548928)     // 294912 float-slots (589824 fp16)
#define WS_PH     ((size_t)9527360)    // 4194304 float-slots (fp16 e-values)
#define WS_MT     ((size_t)13721664)   // 65536  m per (b*h, tile)
#define WS_ST     ((size_t)13787200)   // 65536  sum per (b*h, tile)
#define WS_SC     ((size_t)13852736)   // 65536  scale per (b*h, tile)
#define WS_ATTN   ((size_t)17915968)   // 524288
#define WS_PART   ((size_t)18440256)   // 10485760 (= 256*40960 exactly)
#define WS_PART2  ((size_t)28926016)   // 327680 (= 8*40960)

// ---------------- split-K GEMV: C[8,N] = A[8,K] @ B[K,N] ----------------
// A-slice staged in LDS (transposed); inner loop: 1 global float4 +
// 2 uniform-address ds_read_b128 per k.
__global__ __launch_bounds__(256) void gemv8_splitk(
    const float* __restrict__ A, const float* __restrict__ B,
    float* __restrict__ part, int K, int N, int KC)
{
    __shared__ __align__(16) float As[512][8];   // KC <= 512
    const int k0 = blockIdx.y * KC;
    const int kend = min(k0 + KC, K);
    const int klen = kend - k0;
    for (int i = threadIdx.x; i < klen * 8; i += 256) {
        const int kk = i >> 3, m = i & 7;
        As[kk][m] = A[(size_t)m * K + k0 + kk];
    }
    __syncthreads();
    const int n4 = (blockIdx.x * 256 + threadIdx.x) * 4;
    if (n4 >= N) return;
    float acc[8][4] = {};
    const float* bp = B + (size_t)k0 * N + n4;
    #pragma unroll 4
    for (int k = 0; k < klen; ++k) {
        const float4 bv = *reinterpret_cast<const float4*>(bp);
        bp += N;
        const float4 a0 = *reinterpret_cast<const float4*>(&As[k][0]);
        const float4 a1 = *reinterpret_cast<const float4*>(&As[k][4]);
        const float am[8] = {a0.x, a0.y, a0.z, a0.w, a1.x, a1.y, a1.z, a1.w};
        #pragma unroll
        for (int m = 0; m < 8; ++m) {
            acc[m][0] = fmaf(am[m], bv.x, acc[m][0]);
            acc[m][1] = fmaf(am[m], bv.y, acc[m][1]);
            acc[m][2] = fmaf(am[m], bv.z, acc[m][2]);
            acc[m][3] = fmaf(am[m], bv.w, acc[m][3]);
        }
    }
    float* pp = part + (size_t)blockIdx.y * 8 * N;
    #pragma unroll
    for (int m = 0; m < 8; ++m) {
        float4 o; o.x = acc[m][0]; o.y = acc[m][1]; o.z = acc[m][2]; o.w = acc[m][3];
        *reinterpret_cast<float4*>(pp + (size_t)m * N + n4) = o;
    }
}

// ---------------- RMSNorm two-stage ------------------------------------
__global__ __launch_bounds__(256) void rms_stageA(
    const float* __restrict__ part, float* __restrict__ cqy,
    float* __restrict__ ssp, int splits)
{
    const int nb = blockIdx.x, m = blockIdx.y;
    const int n = nb * 256 + threadIdx.x;
    float y = 0.f;
    #pragma unroll 8
    for (int s = 0; s < splits; ++s) y += part[((size_t)s * 8 + m) * QLR_D + n];
    cqy[(size_t)m * QLR_D + n] = y;
    __shared__ float red[256];
    red[threadIdx.x] = y * y; __syncthreads();
    for (int st = 128; st > 0; st >>= 1) {
        if (threadIdx.x < st) red[threadIdx.x] += red[threadIdx.x + st];
        __syncthreads();
    }
    if (threadIdx.x == 0) ssp[m * 6 + nb] = red[0];
}

__global__ __launch_bounds__(256) void rms_stageB(
    const float* __restrict__ cqy, const float* __restrict__ ssp,
    const float* __restrict__ w, float* __restrict__ cq)
{
    const int m = blockIdx.x;
    float ss = 0.f;
    #pragma unroll
    for (int j = 0; j < 6; ++j) ss += ssp[m * 6 + j];
    const float r = 1.0f / sqrtf(ss / (float)QLR_D + 1e-6f);
    for (int n = threadIdx.x; n < QLR_D; n += 256)
        cq[(size_t)m * QLR_D + n] = w[n] * cqy[(size_t)m * QLR_D + n] * r;
}

// ---------------- reduce q_pe partials + RoPE(pos 8191) -> qh fp16 ------
__global__ __launch_bounds__(256) void reduce_rope_q(
    const float* __restrict__ part, _Float16* __restrict__ qh, int splits)
{
    const int idx = blockIdx.x * 256 + threadIdx.x;
    if (idx >= B_SZ * NHEAD * 32) return;
    const int p = idx & 31, h = (idx >> 5) & (NHEAD - 1), m = idx >> 12;
    const int N = NHEAD * ROPE_D;
    const int n0 = h * ROPE_D + 2 * p;
    float x0 = 0.f, x1 = 0.f;
    for (int s = 0; s < splits; ++s) {
        const float* pp = part + ((size_t)s * 8 + m) * N + n0;
        x0 += pp[0]; x1 += pp[1];
    }
    const double inv = pow(10000.0, -(double)p / 32.0);
    const float ang = 8191.0f * (float)inv;
    const double c = cos((double)ang), sn = sin((double)ang);
    const float r0 = (float)((double)x0 * c - (double)x1 * sn);
    const float r1 = (float)((double)x0 * sn + (double)x1 * c);
    const size_t o = ((size_t)m * NHEAD + h) * 576 + 2 * p;
    f16x2 v; v[0] = (_Float16)r0; v[1] = (_Float16)r1;
    *reinterpret_cast<f16x2*>(qh + o) = v;
}

// ---------------- reduce q_nope partials (16 splits) -> qh fp16 ---------
__global__ __launch_bounds__(256) void reduce_convert_q(
    const float* __restrict__ part, _Float16* __restrict__ qh)
{
    const int t = blockIdx.x * 256 + threadIdx.x;
    const size_t i4 = (size_t)t * 4;
    if (i4 >= (size_t)B_SZ * NHEAD * 512) return;
    float4 acc = make_float4(0.f, 0.f, 0.f, 0.f);
    #pragma unroll
    for (int s = 0; s < 16; ++s) {
        const float4 v = *reinterpret_cast<const float4*>(part + (size_t)s * 524288 + i4);
        acc.x += v.x; acc.y += v.y; acc.z += v.z; acc.w += v.w;
    }
    const int c = (int)(i4 & 511), bh = (int)(i4 >> 9);
    const size_t o = (size_t)bh * 576 + 64 + c;
    f16x4 vh;
    vh[0] = (_Float16)acc.x; vh[1] = (_Float16)acc.y;
    vh[2] = (_Float16)acc.z; vh[3] = (_Float16)acc.w;
    *reinterpret_cast<f16x4*>(qh + o) = vh;
}

// ---------------- trig table: [k][p] cos/sin ----------------------------
__global__ __launch_bounds__(256) void trig_table_kernel(float2* __restrict__ tab)
{
    const int idx = blockIdx.x * 256 + threadIdx.x;
    if (idx >= KVLEN * 32) return;
    const int k = idx >> 5, p = idx & 31;
    const double inv = pow(10000.0, -(double)p / 32.0);
    const float ang = (float)k * (float)inv;
    tab[idx] = make_float2((float)cos((double)ang), (float)sin((double)ang));
}

// ---------------- scores + tile-softmax via fp16 MFMA -------------------
// block: 128 heads x 128 keys; grid (64 key-chunks, 8 b); 256 thr = 4 waves
__global__ __launch_bounds__(256) void scores_mfma(
    const _Float16* __restrict__ qh,
    const float* __restrict__ kpe, const float* __restrict__ ckv,
    const float2* __restrict__ tab, _Float16* __restrict__ ph,
    float* __restrict__ mtab, float* __restrict__ stab)
{
    const int b = blockIdx.y;
    const int k0 = blockIdx.x * 128;
    __shared__ __align__(16) _Float16 kbuf[2][128][64];  // logical chunks 0-3, ^(row&7)
    __shared__ float redm[2][128];
    __shared__ float reds[2][128];
    const int tid = threadIdx.x, lane = tid & 63, w = tid >> 6;
    const int hbase = (w >> 1) * 64, kbw = (w & 1) * 64;
    const int skey = tid >> 1, shalf = tid & 1;
    const int hgrp = lane >> 4;
    f32x4 acc[4][4] = {};

    float v[16];
    float2 cs[8];
    {
        const float* src = kpe + ((size_t)(b * KVLEN + k0 + skey)) * 64 + shalf * 16;
        #pragma unroll
        for (int q = 0; q < 4; ++q) {
            const float4 f = *reinterpret_cast<const float4*>(src + q * 4);
            v[q*4+0] = f.x; v[q*4+1] = f.y; v[q*4+2] = f.z; v[q*4+3] = f.w;
        }
        const float2* tp = tab + (size_t)(k0 + skey) * 32 + shalf * 8;
        #pragma unroll
        for (int j = 0; j < 8; ++j) cs[j] = tp[j];
    }
    f16x8 a[4];
    #pragma unroll
    for (int hs = 0; hs < 4; ++hs) {
        const size_t qoff = ((size_t)(b * NHEAD + hbase + hs * 16 + (lane & 15))) * 576
                            + (lane >> 4) * 8;
        a[hs] = *reinterpret_cast<const f16x8*>(qh + qoff);
    }

    for (int s = 0; s < 18; ++s) {
        const int c0 = s * 32;
        float x[16];
        if (c0 < 64) {
            #pragma unroll
            for (int j = 0; j < 8; ++j) {
                const float x0 = v[2*j], x1 = v[2*j+1];
                x[2*j]   = x0 * cs[j].x - x1 * cs[j].y;
                x[2*j+1] = x0 * cs[j].y + x1 * cs[j].x;
            }
        } else {
            #pragma unroll
            for (int j = 0; j < 16; ++j) x[j] = v[j];
        }
        f16x8 h0, h1;
        #pragma unroll
        for (int e = 0; e < 8; ++e) { h0[e] = (_Float16)x[e]; h1[e] = (_Float16)x[8+e]; }
        {
            f16x8* rowp = reinterpret_cast<f16x8*>(&kbuf[s & 1][skey][0]);
            const int r7 = skey & 7;
            rowp[(shalf * 2 + 0) ^ r7] = h0;
            rowp[(shalf * 2 + 1) ^ r7] = h1;
        }
        __syncthreads();
        f16x8 na[4];
        if (s + 1 < 18) {
            const int c1 = c0 + 32;
            if (c1 < 64) {
                const float* src = kpe + ((size_t)(b * KVLEN + k0 + skey)) * 64 + c1 + shalf * 16;
                #pragma unroll
                for (int q = 0; q < 4; ++q) {
                    const float4 f = *reinterpret_cast<const float4*>(src + q * 4);
                    v[q*4+0] = f.x; v[q*4+1] = f.y; v[q*4+2] = f.z; v[q*4+3] = f.w;
                }
                const float2* tp = tab + (size_t)(k0 + skey) * 32 + c1 / 2 + shalf * 8;
                #pragma unroll
                for (int j = 0; j < 8; ++j) cs[j] = tp[j];
            } else {
                const float* src = ckv + ((size_t)(b * KVLEN + k0 + skey)) * 512 + (c1 - 64) + shalf * 16;
                #pragma unroll
                for (int q = 0; q < 4; ++q) {
                    const float4 f = *reinterpret_cast<const float4*>(src + q * 4);
                    v[q*4+0] = f.x; v[q*4+1] = f.y; v[q*4+2] = f.z; v[q*4+3] = f.w;
                }
            }
            #pragma unroll
            for (int hs = 0; hs < 4; ++hs) {
                const size_t qoff = ((size_t)(b * NHEAD + hbase + hs * 16 + (lane & 15))) * 576
                                    + c1 + (lane >> 4) * 8;
                na[hs] = *reinterpret_cast<const f16x8*>(qh + qoff);
            }
        }
        #pragma unroll
        for (int ks = 0; ks < 4; ++ks) {
            const int row = kbw + ks * 16 + (lane & 15);
            const f16x8* rp = reinterpret_cast<const f16x8*>(&kbuf[s & 1][row][0]);
            const int r7 = row & 7;
            const f16x8 bf = rp[(lane >> 4) ^ r7];
            #pragma unroll
            for (int hs = 0; hs < 4; ++hs)
                acc[hs][ks] = __builtin_amdgcn_mfma_f32_16x16x32_f16(a[hs], bf, acc[hs][ks], 0, 0, 0);
        }
        if (s + 1 < 18) {
            #pragma unroll
            for (int hs = 0; hs < 4; ++hs) a[hs] = na[hs];
        }
    }

    // ---- epilogue: tile-local softmax ----
    #pragma unroll
    for (int hs = 0; hs < 4; ++hs)
        #pragma unroll
        for (int ks = 0; ks < 4; ++ks)
            acc[hs][ks] = acc[hs][ks] * SCALE_F;
    float mrow[4][4];
    #pragma unroll
    for (int hs = 0; hs < 4; ++hs)
        #pragma unroll
        for (int r = 0; r < 4; ++r) {
            float m = fmaxf(fmaxf(acc[hs][0][r], acc[hs][1][r]),
                            fmaxf(acc[hs][2][r], acc[hs][3][r]));
            m = fmaxf(m, __shfl_xor(m, 1, 64));
            m = fmaxf(m, __shfl_xor(m, 2, 64));
            m = fmaxf(m, __shfl_xor(m, 4, 64));
            m = fmaxf(m, __shfl_xor(m, 8, 64));
            mrow[hs][r] = m;
        }
    if ((lane & 15) == 0) {
        #pragma unroll
        for (int hs = 0; hs < 4; ++hs)
            #pragma unroll
            for (int r = 0; r < 4; ++r)
                redm[w & 1][hbase + hs * 16 + hgrp * 4 + r] = mrow[hs][r];
    }
    __syncthreads();
    #pragma unroll
    for (int hs = 0; hs < 4; ++hs)
        #pragma unroll
        for (int r = 0; r < 4; ++r) {
            const int head = hbase + hs * 16 + hgrp * 4 + r;
            mrow[hs][r] = fmaxf(redm[0][head], redm[1][head]);
        }
    float srow[4][4] = {};
    #pragma unroll
    for (int hs = 0; hs < 4; ++hs)
        #pragma unroll
        for (int ks = 0; ks < 4; ++ks)
            #pragma unroll
            for (int r = 0; r < 4; ++r) {
                const float e = expf(acc[hs][ks][r] - mrow[hs][r]);
                srow[hs][r] += e;
                const int head = hbase + hs * 16 + hgrp * 4 + r;
                const int key  = k0 + kbw + ks * 16 + (lane & 15);
                ph[((size_t)(b * NHEAD + head)) * KVLEN + key] = (_Float16)e;
            }
    #pragma unroll
    for (int hs = 0; hs < 4; ++hs)
        #pragma unroll
        for (int r = 0; r < 4; ++r) {
            float s = srow[hs][r];
            s += __shfl_xor(s, 1, 64);
            s += __shfl_xor(s, 2, 64);
            s += __shfl_xor(s, 4, 64);
            s += __shfl_xor(s, 8, 64);
            srow[hs][r] = s;
        }
    if ((lane & 15) == 0) {
        #pragma unroll
        for (int hs = 0; hs < 4; ++hs)
            #pragma unroll
            for (int r = 0; r < 4; ++r)
                reds[w & 1][hbase + hs * 16 + hgrp * 4 + r] = srow[hs][r];
    }
    __syncthreads();
    if ((w & 1) == 0 && (lane & 15) == 0) {
        #pragma unroll
        for (int hs = 0; hs < 4; ++hs)
            #pragma unroll
            for (int r = 0; r < 4; ++r) {
                const int head = hbase + hs * 16 + hgrp * 4 + r;
                const size_t o = ((size_t)(b * NHEAD + head)) * 64 + blockIdx.x;
                mtab[o] = mrow[hs][r];
                stab[o] = reds[0][head] + reds[1][head];
            }
    }
}

// ---------------- combine: one wave per (b,h) row -----------------------
__global__ __launch_bounds__(256) void softmax_combine(
    const float* __restrict__ mtab, const float* __restrict__ stab,
    float* __restrict__ scales)
{
    const int wv = threadIdx.x >> 6, lane = threadIdx.x & 63;
    const int r = blockIdx.x * 4 + wv;          // b*NHEAD + h
    const float m = mtab[(size_t)r * 64 + lane];
    const float s = stab[(size_t)r * 64 + lane];
    float M = m;
    #pragma unroll
    for (int off = 32; off >= 1; off >>= 1) M = fmaxf(M, __shfl_xor(M, off, 64));
    const float e = expf(m - M);
    float S = s * e;
    #pragma unroll
    for (int off = 32; off >= 1; off >>= 1) S += __shfl_xor(S, off, 64);
    scales[(size_t)r * 64 + lane] = e / S;
}

// ---------------- PV via fp16 MFMA (e*scale x V), dbuf ------------------
// block: 128 heads x 256 l, key-chunk 512; grid (2 l-tiles, 16 ks, 8 b)
__global__ __launch_bounds__(256, 1) void pv_mfma(
    const _Float16* __restrict__ ph, const float* __restrict__ scales,
    const float* __restrict__ ckv, float* __restrict__ part)
{
    const int lt = blockIdx.x, ks = blockIdx.y, b = blockIdx.z;
    const int l0 = lt * 256;
    __shared__ __align__(16) _Float16 vbuf[2][256][64];  // chunks 0-3 used, ^(row&7)
    const int tid = threadIdx.x, lane = tid & 63, w = tid >> 6;
    const int hbase = (w >> 1) * 64, lbw = (w & 1) * 128;
    const int lq = (tid & 63) * 4;
    const int kb = (tid >> 6) * 8;
    f32x4 acc[4][8] = {};
    const int kstart = ks * 512;

    float4 v4[8];
    #pragma unroll
    for (int e = 0; e < 8; ++e)
        v4[e] = *reinterpret_cast<const float4*>(
            ckv + ((size_t)(b * KVLEN + kstart + kb + e)) * 512 + l0 + lq);
    f16x8 a[4];
    float sc_h[4];
    #pragma unroll
    for (int hs = 0; hs < 4; ++hs) {
        const int head = hbase + hs * 16 + (lane & 15);
        const size_t poff = ((size_t)(b * NHEAD + head)) * KVLEN
                            + kstart + (lane >> 4) * 8;
        a[hs] = *reinterpret_cast<const f16x8*>(ph + poff);
        sc_h[hs] = scales[((size_t)(b * NHEAD + head)) * 64 + (kstart >> 7)];
    }

    for (int s = 0; s < 16; ++s) {
        const float vv[8][4] = {
            {v4[0].x, v4[0].y, v4[0].z, v4[0].w}, {v4[1].x, v4[1].y, v4[1].z, v4[1].w},
            {v4[2].x, v4[2].y, v4[2].z, v4[2].w}, {v4[3].x, v4[3].y, v4[3].z, v4[3].w},
            {v4[4].x, v4[4].y, v4[4].z, v4[4].w}, {v4[5].x, v4[5].y, v4[5].z, v4[5].w},
            {v4[6].x, v4[6].y, v4[6].z, v4[6].w}, {v4[7].x, v4[7].y, v4[7].z, v4[7].w}};
        #pragma unroll
        for (int j = 0; j < 4; ++j) {
            f16x8 h8;
            #pragma unroll
            for (int e = 0; e < 8; ++e) h8[e] = (_Float16)vv[e][j];
            const int row = lq + j, r7 = row & 7;
            f16x8* rowp = reinterpret_cast<f16x8*>(&vbuf[s & 1][row][0]);
            rowp[(kb >> 3) ^ r7] = h8;
        }
        // scale A-frags (e-values * per-tile scale)
        f16x8 as[4];
        #pragma unroll
        for (int hs = 0; hs < 4; ++hs) {
            const float sc = sc_h[hs];
            #pragma unroll
            for (int e = 0; e < 8; ++e)
                as[hs][e] = (_Float16)((float)a[hs][e] * sc);
        }
        __syncthreads();
        f16x8 na[4];
        float nsc[4];
        if (s + 1 < 16) {
            const int kk = kstart + (s + 1) * 32;
            #pragma unroll
            for (int e = 0; e < 8; ++e)
                v4[e] = *reinterpret_cast<const float4*>(
                    ckv + ((size_t)(b * KVLEN + kk + kb + e)) * 512 + l0 + lq);
            #pragma unroll
            for (int hs = 0; hs < 4; ++hs) {
                const int head = hbase + hs * 16 + (lane & 15);
                const size_t poff = ((size_t)(b * NHEAD + head)) * KVLEN
                                    + kk + (lane >> 4) * 8;
                na[hs] = *reinterpret_cast<const f16x8*>(ph + poff);
                nsc[hs] = scales[((size_t)(b * NHEAD + head)) * 64 + (kk >> 7)];
            }
        }
        #pragma unroll
        for (int ls = 0; ls < 8; ++ls) {
            const int row = lbw + ls * 16 + (lane & 15);
            const f16x8* rp = reinterpret_cast<const f16x8*>(&vbuf[s & 1][row][0]);
            const int r7 = row & 7;
            const f16x8 vf = rp[(lane >> 4) ^ r7];
            #pragma unroll
            for (int hs = 0; hs < 4; ++hs)
                acc[hs][ls] = __builtin_amdgcn_mfma_f32_16x16x32_f16(as[hs], vf, acc[hs][ls], 0, 0, 0);
        }
        if (s + 1 < 16) {
            #pragma unroll
            for (int hs = 0; hs < 4; ++hs) { a[hs] = na[hs]; sc_h[hs] = nsc[hs]; }
        }
    }
    #pragma unroll
    for (int hs = 0; hs < 4; ++hs)
        #pragma unroll
        for (int ls = 0; ls < 8; ++ls)
            #pragma unroll
            for (int r = 0; r < 4; ++r) {
                const int head = hbase + hs * 16 + (lane >> 4) * 4 + r;
                const int l    = l0 + lbw + ls * 16 + (lane & 15);
                part[(((size_t)ks * B_SZ + b) * NHEAD + head) * KVLR_D + l] = acc[hs][ls][r];
            }
}

// ---------------- attn reduce (16 splits, float4) -----------------------
__global__ __launch_bounds__(256) void reduce_attn(
    const float* __restrict__ part, float* __restrict__ attn)
{
    const int t = blockIdx.x * 256 + threadIdx.x;
    const size_t i4 = (size_t)t * 4;
    if (i4 >= (size_t)524288) return;
    float4 acc = make_float4(0.f, 0.f, 0.f, 0.f);
    #pragma unroll
    for (int s = 0; s < 16; ++s) {
        const float4 v = *reinterpret_cast<const float4*>(part + (size_t)s * 524288 + i4);
        acc.x += v.x; acc.y += v.y; acc.z += v.z; acc.w += v.w;
    }
    *reinterpret_cast<float4*>(attn + i4) = acc;
}

// ---------------- final output reduce, two stages -----------------------
__global__ __launch_bounds__(256) void final_r1(
    const float* __restrict__ part, float* __restrict__ part2)
{
    const int t = blockIdx.x * 256 + threadIdx.x;   // 10240 threads
    const size_t i4 = (size_t)t * 4;
    const int sg = blockIdx.y;
    float4 acc = make_float4(0.f, 0.f, 0.f, 0.f);
    #pragma unroll 8
    for (int s = 0; s < 32; ++s) {
        const float4 v = *reinterpret_cast<const float4*>(
            part + ((size_t)(sg * 32 + s)) * 40960 + i4);
        acc.x += v.x; acc.y += v.y; acc.z += v.z; acc.w += v.w;
    }
    *reinterpret_cast<float4*>(part2 + (size_t)sg * 40960 + i4) = acc;
}

__global__ __launch_bounds__(256) void final_r2(
    const float* __restrict__ part2, float* __restrict__ out)
{
    const int t = blockIdx.x * 256 + threadIdx.x;
    const size_t i4 = (size_t)t * 4;
    float4 acc = make_float4(0.f, 0.f, 0.f, 0.f);
    #pragma unroll
    for (int s = 0; s < 8; ++s) {
        const float4 v = *reinterpret_cast<const float4*>(part2 + (size_t)s * 40960 + i4);
        acc.x += v.x; acc.y += v.y; acc.z += v.z; acc.w += v.w;
    }
    *reinterpret_cast<float4*>(out + i4) = acc;
}

extern "C" void kernel_launch(void* const* d_in, const int* in_sizes, int n_in,
                              void* d_out, int out_size, void* d_ws, size_t ws_size,
                              hipStream_t stream)
{
    const float* hidden  = (const float*)d_in[0];
    const float* ckv     = (const float*)d_in[1];
    const float* kpe     = (const float*)d_in[2];
    const float* W_DQ    = (const float*)d_in[3];
    const float* ln_w    = (const float*)d_in[4];
    const float* W_QR    = (const float*)d_in[5];
    const float* W_UQ_UK = (const float*)d_in[6];
    const float* W_UV_O  = (const float*)d_in[7];
    float* out = (float*)d_out;
    float* ws  = (float*)d_ws;

    float* cqy    = ws + WS_CQY;
    float* ssp    = ws + WS_SSP;
    float* cq     = ws + WS_CQ;
    float2* trig  = (float2*)(ws + WS_TRIG);
    _Float16* qh  = (_Float16*)(ws + WS_QH);
    _Float16* prh = (_Float16*)(ws + WS_PH);
    float* mtab   = ws + WS_MT;
    float* stab   = ws + WS_ST;
    float* scales = ws + WS_SC;
    float* attn   = ws + WS_ATTN;
    float* part   = ws + WS_PART;
    float* part2  = ws + WS_PART2;

    // trig table first (independent)
    trig_table_kernel<<<1024, 256, 0, stream>>>(trig);
    // 1. cQ = rmsnorm(hidden @ W_DQ)
    gemv8_splitk<<<dim3(2, 80), 256, 0, stream>>>(hidden, W_DQ, part, H_DIM, QLR_D, 64);
    rms_stageA<<<dim3(6, 8), 256, 0, stream>>>(part, cqy, ssp, 80);
    rms_stageB<<<8, 256, 0, stream>>>(cqy, ssp, ln_w, cq);
    // 2. q_pe = rope(cQ @ W_QR) -> qh[0:64]
    gemv8_splitk<<<dim3(8, 32), 256, 0, stream>>>(cq, W_QR, part, QLR_D, NHEAD * ROPE_D, 48);
    reduce_rope_q<<<128, 256, 0, stream>>>(part, qh, 32);
    // 3. q_nope = cQ @ W_UQ_UK -> qh[64:576]  (16 splits, 1024 blocks = 4/CU)
    gemv8_splitk<<<dim3(64, 16), 256, 0, stream>>>(cq, W_UQ_UK, part, QLR_D, NHEAD * KVLR_D, 96);
    reduce_convert_q<<<512, 256, 0, stream>>>(part, qh);
    // 4. scores + tile-softmax (fused k_pe RoPE) -> fp16 e-values + m/s tables
    scores_mfma<<<dim3(64, 8), 256, 0, stream>>>(qh, kpe, ckv, trig, prh, mtab, stab);
    // 5. combine -> per-tile scales (wave-parallel)
    softmax_combine<<<256, 256, 0, stream>>>(mtab, stab, scales);
    // 6. attn = (e*scale) @ ckv (split-K 16, 2 l-tiles)
    pv_mfma<<<dim3(2, 16, 8), 256, 0, stream>>>(prh, scales, ckv, part);
    reduce_attn<<<512, 256, 0, stream>>>(part, attn);
    // 7. out = attn @ W_UV_O (256 splits, 1280 blocks = 5/CU)
    gemv8_splitk<<<dim3(5, 256), 256, 0, stream>>>(attn, W_UV_O, part, NHEAD * KVLR_D, H_DIM, 256);
    final_r1<<<dim3(40, 8), 256, 0, stream>>>(part, part2);
    final_r2<<<40, 256, 0, stream>>>(part2, out);
}

// Round 11
// 485.132 us; speedup vs baseline: 1.0486x; 1.0486x over previous
//
#include <hip/hip_runtime.h>
#include <cmath>

#define B_SZ   8
#define H_DIM  5120
#define NHEAD  128
#define QLR_D  1536
#define ROPE_D 64
#define KVLR_D 512
#define KVLEN  8192
#define SCALE_F 0.07216878364870322f  // 192^-0.5

typedef _Float16 f16x8 __attribute__((ext_vector_type(8)));
typedef _Float16 f16x4 __attribute__((ext_vector_type(4)));
typedef _Float16 f16x2 __attribute__((ext_vector_type(2)));
typedef __attribute__((ext_vector_type(4))) float f32x4;

// ws layout (float offsets)
#define WS_CQY    ((size_t)0)          // 12288
#define WS_SSP    ((size_t)12288)      // 64
#define WS_CQ     ((size_t)12352)      // 12288
#define WS_TRIG   ((size_t)24640)      // 524288 (8192*32 float2)
#define WS_QH     ((size_t)548928)     // 294912 float-slots (589824 fp16)
#define WS_PH     ((size_t)9527360)    // 4194304 float-slots (fp16 e-values)
#define WS_MT     ((size_t)13721664)   // 65536  m per (b*h, tile)
#define WS_ST     ((size_t)13787200)   // 65536  sum per (b*h, tile)
#define WS_SC     ((size_t)13852736)   // 65536  scale per (b*h, tile)
#define WS_ATTN   ((size_t)17915968)   // 524288
#define WS_PART   ((size_t)18440256)   // 10485760
#define WS_PART2  ((size_t)28926016)   // 327680

// ---------------- split-K GEMV: C[8,N] = A[8,K] @ B[K,N] ----------------
// A-slice staged in LDS (transposed); inner loop: 1 global float4 +
// 2 uniform-address ds_read_b128 per k.
__global__ __launch_bounds__(256) void gemv8_splitk(
    const float* __restrict__ A, const float* __restrict__ B,
    float* __restrict__ part, int K, int N, int KC)
{
    __shared__ __align__(16) float As[512][8];   // KC <= 512
    const int k0 = blockIdx.y * KC;
    const int kend = min(k0 + KC, K);
    const int klen = kend - k0;
    for (int i = threadIdx.x; i < klen * 8; i += 256) {
        const int kk = i >> 3, m = i & 7;
        As[kk][m] = A[(size_t)m * K + k0 + kk];
    }
    __syncthreads();
    const int n4 = (blockIdx.x * 256 + threadIdx.x) * 4;
    if (n4 >= N) return;
    float acc[8][4] = {};
    const float* bp = B + (size_t)k0 * N + n4;
    #pragma unroll 4
    for (int k = 0; k < klen; ++k) {
        const float4 bv = *reinterpret_cast<const float4*>(bp);
        bp += N;
        const float4 a0 = *reinterpret_cast<const float4*>(&As[k][0]);
        const float4 a1 = *reinterpret_cast<const float4*>(&As[k][4]);
        const float am[8] = {a0.x, a0.y, a0.z, a0.w, a1.x, a1.y, a1.z, a1.w};
        #pragma unroll
        for (int m = 0; m < 8; ++m) {
            acc[m][0] = fmaf(am[m], bv.x, acc[m][0]);
            acc[m][1] = fmaf(am[m], bv.y, acc[m][1]);
            acc[m][2] = fmaf(am[m], bv.z, acc[m][2]);
            acc[m][3] = fmaf(am[m], bv.w, acc[m][3]);
        }
    }
    float* pp = part + (size_t)blockIdx.y * 8 * N;
    #pragma unroll
    for (int m = 0; m < 8; ++m) {
        float4 o; o.x = acc[m][0]; o.y = acc[m][1]; o.z = acc[m][2]; o.w = acc[m][3];
        *reinterpret_cast<float4*>(pp + (size_t)m * N + n4) = o;
    }
}

// ---------------- RMSNorm two-stage ------------------------------------
__global__ __launch_bounds__(256) void rms_stageA(
    const float* __restrict__ part, float* __restrict__ cqy,
    float* __restrict__ ssp, int splits)
{
    const int nb = blockIdx.x, m = blockIdx.y;
    const int n = nb * 256 + threadIdx.x;
    float y = 0.f;
    #pragma unroll 8
    for (int s = 0; s < splits; ++s) y += part[((size_t)s * 8 + m) * QLR_D + n];
    cqy[(size_t)m * QLR_D + n] = y;
    __shared__ float red[256];
    red[threadIdx.x] = y * y; __syncthreads();
    for (int st = 128; st > 0; st >>= 1) {
        if (threadIdx.x < st) red[threadIdx.x] += red[threadIdx.x + st];
        __syncthreads();
    }
    if (threadIdx.x == 0) ssp[m * 6 + nb] = red[0];
}

__global__ __launch_bounds__(256) void rms_stageB(
    const float* __restrict__ cqy, const float* __restrict__ ssp,
    const float* __restrict__ w, float* __restrict__ cq)
{
    const int m = blockIdx.x;
    float ss = 0.f;
    #pragma unroll
    for (int j = 0; j < 6; ++j) ss += ssp[m * 6 + j];
    const float r = 1.0f / sqrtf(ss / (float)QLR_D + 1e-6f);
    for (int n = threadIdx.x; n < QLR_D; n += 256)
        cq[(size_t)m * QLR_D + n] = w[n] * cqy[(size_t)m * QLR_D + n] * r;
}

// ---------------- reduce q_pe partials + RoPE(pos 8191) -> qh fp16 ------
__global__ __launch_bounds__(256) void reduce_rope_q(
    const float* __restrict__ part, _Float16* __restrict__ qh, int splits)
{
    const int idx = blockIdx.x * 256 + threadIdx.x;
    if (idx >= B_SZ * NHEAD * 32) return;
    const int p = idx & 31, h = (idx >> 5) & (NHEAD - 1), m = idx >> 12;
    const int N = NHEAD * ROPE_D;
    const int n0 = h * ROPE_D + 2 * p;
    float x0 = 0.f, x1 = 0.f;
    for (int s = 0; s < splits; ++s) {
        const float* pp = part + ((size_t)s * 8 + m) * N + n0;
        x0 += pp[0]; x1 += pp[1];
    }
    const double inv = pow(10000.0, -(double)p / 32.0);
    const float ang = 8191.0f * (float)inv;
    const double c = cos((double)ang), sn = sin((double)ang);
    const float r0 = (float)((double)x0 * c - (double)x1 * sn);
    const float r1 = (float)((double)x0 * sn + (double)x1 * c);
    const size_t o = ((size_t)m * NHEAD + h) * 576 + 2 * p;
    f16x2 v; v[0] = (_Float16)r0; v[1] = (_Float16)r1;
    *reinterpret_cast<f16x2*>(qh + o) = v;
}

// ---------------- reduce q_nope partials (8 splits) -> qh fp16 ----------
__global__ __launch_bounds__(256) void reduce_convert_q(
    const float* __restrict__ part, _Float16* __restrict__ qh)
{
    const int t = blockIdx.x * 256 + threadIdx.x;
    const size_t i4 = (size_t)t * 4;
    if (i4 >= (size_t)B_SZ * NHEAD * 512) return;
    float4 acc = make_float4(0.f, 0.f, 0.f, 0.f);
    #pragma unroll
    for (int s = 0; s < 8; ++s) {
        const float4 v = *reinterpret_cast<const float4*>(part + (size_t)s * 524288 + i4);
        acc.x += v.x; acc.y += v.y; acc.z += v.z; acc.w += v.w;
    }
    const int c = (int)(i4 & 511), bh = (int)(i4 >> 9);
    const size_t o = (size_t)bh * 576 + 64 + c;
    f16x4 vh;
    vh[0] = (_Float16)acc.x; vh[1] = (_Float16)acc.y;
    vh[2] = (_Float16)acc.z; vh[3] = (_Float16)acc.w;
    *reinterpret_cast<f16x4*>(qh + o) = vh;
}

// ---------------- trig table: [k][p] cos/sin ----------------------------
__global__ __launch_bounds__(256) void trig_table_kernel(float2* __restrict__ tab)
{
    const int idx = blockIdx.x * 256 + threadIdx.x;
    if (idx >= KVLEN * 32) return;
    const int k = idx >> 5, p = idx & 31;
    const double inv = pow(10000.0, -(double)p / 32.0);
    const float ang = (float)k * (float)inv;
    tab[idx] = make_float2((float)cos((double)ang), (float)sin((double)ang));
}

// ---------------- scores + tile-softmax via fp16 MFMA -------------------
// block: 128 heads x 128 keys; grid (64 key-chunks, 8 b); 256 thr = 4 waves
__global__ __launch_bounds__(256) void scores_mfma(
    const _Float16* __restrict__ qh,
    const float* __restrict__ kpe, const float* __restrict__ ckv,
    const float2* __restrict__ tab, _Float16* __restrict__ ph,
    float* __restrict__ mtab, float* __restrict__ stab)
{
    const int b = blockIdx.y;
    const int k0 = blockIdx.x * 128;
    __shared__ __align__(16) _Float16 kbuf[2][128][64];  // logical chunks 0-3, ^(row&7)
    __shared__ float redm[2][128];
    __shared__ float reds[2][128];
    const int tid = threadIdx.x, lane = tid & 63, w = tid >> 6;
    const int hbase = (w >> 1) * 64, kbw = (w & 1) * 64;
    const int skey = tid >> 1, shalf = tid & 1;
    const int hgrp = lane >> 4;
    f32x4 acc[4][4] = {};

    float v[16];
    float2 cs[8];
    {
        const float* src = kpe + ((size_t)(b * KVLEN + k0 + skey)) * 64 + shalf * 16;
        #pragma unroll
        for (int q = 0; q < 4; ++q) {
            const float4 f = *reinterpret_cast<const float4*>(src + q * 4);
            v[q*4+0] = f.x; v[q*4+1] = f.y; v[q*4+2] = f.z; v[q*4+3] = f.w;
        }
        const float2* tp = tab + (size_t)(k0 + skey) * 32 + shalf * 8;
        #pragma unroll
        for (int j = 0; j < 8; ++j) cs[j] = tp[j];
    }
    f16x8 a[4];
    #pragma unroll
    for (int hs = 0; hs < 4; ++hs) {
        const size_t qoff = ((size_t)(b * NHEAD + hbase + hs * 16 + (lane & 15))) * 576
                            + (lane >> 4) * 8;
        a[hs] = *reinterpret_cast<const f16x8*>(qh + qoff);
    }

    for (int s = 0; s < 18; ++s) {
        const int c0 = s * 32;
        float x[16];
        if (c0 < 64) {
            #pragma unroll
            for (int j = 0; j < 8; ++j) {
                const float x0 = v[2*j], x1 = v[2*j+1];
                x[2*j]   = x0 * cs[j].x - x1 * cs[j].y;
                x[2*j+1] = x0 * cs[j].y + x1 * cs[j].x;
            }
        } else {
            #pragma unroll
            for (int j = 0; j < 16; ++j) x[j] = v[j];
        }
        f16x8 h0, h1;
        #pragma unroll
        for (int e = 0; e < 8; ++e) { h0[e] = (_Float16)x[e]; h1[e] = (_Float16)x[8+e]; }
        {
            f16x8* rowp = reinterpret_cast<f16x8*>(&kbuf[s & 1][skey][0]);
            const int r7 = skey & 7;
            rowp[(shalf * 2 + 0) ^ r7] = h0;
            rowp[(shalf * 2 + 1) ^ r7] = h1;
        }
        __syncthreads();
        f16x8 na[4];
        if (s + 1 < 18) {
            const int c1 = c0 + 32;
            if (c1 < 64) {
                const float* src = kpe + ((size_t)(b * KVLEN + k0 + skey)) * 64 + c1 + shalf * 16;
                #pragma unroll
                for (int q = 0; q < 4; ++q) {
                    const float4 f = *reinterpret_cast<const float4*>(src + q * 4);
                    v[q*4+0] = f.x; v[q*4+1] = f.y; v[q*4+2] = f.z; v[q*4+3] = f.w;
                }
                const float2* tp = tab + (size_t)(k0 + skey) * 32 + c1 / 2 + shalf * 8;
                #pragma unroll
                for (int j = 0; j < 8; ++j) cs[j] = tp[j];
            } else {
                const float* src = ckv + ((size_t)(b * KVLEN + k0 + skey)) * 512 + (c1 - 64) + shalf * 16;
                #pragma unroll
                for (int q = 0; q < 4; ++q) {
                    const float4 f = *reinterpret_cast<const float4*>(src + q * 4);
                    v[q*4+0] = f.x; v[q*4+1] = f.y; v[q*4+2] = f.z; v[q*4+3] = f.w;
                }
            }
            #pragma unroll
            for (int hs = 0; hs < 4; ++hs) {
                const size_t qoff = ((size_t)(b * NHEAD + hbase + hs * 16 + (lane & 15))) * 576
                                    + c1 + (lane >> 4) * 8;
                na[hs] = *reinterpret_cast<const f16x8*>(qh + qoff);
            }
        }
        #pragma unroll
        for (int ks = 0; ks < 4; ++ks) {
            const int row = kbw + ks * 16 + (lane & 15);
            const f16x8* rp = reinterpret_cast<const f16x8*>(&kbuf[s & 1][row][0]);
            const int r7 = row & 7;
            const f16x8 bf = rp[(lane >> 4) ^ r7];
            #pragma unroll
            for (int hs = 0; hs < 4; ++hs)
                acc[hs][ks] = __builtin_amdgcn_mfma_f32_16x16x32_f16(a[hs], bf, acc[hs][ks], 0, 0, 0);
        }
        if (s + 1 < 18) {
            #pragma unroll
            for (int hs = 0; hs < 4; ++hs) a[hs] = na[hs];
        }
    }

    // ---- epilogue: tile-local softmax ----
    #pragma unroll
    for (int hs = 0; hs < 4; ++hs)
        #pragma unroll
        for (int ks = 0; ks < 4; ++ks)
            acc[hs][ks] = acc[hs][ks] * SCALE_F;
    float mrow[4][4];
    #pragma unroll
    for (int hs = 0; hs < 4; ++hs)
        #pragma unroll
        for (int r = 0; r < 4; ++r) {
            float m = fmaxf(fmaxf(acc[hs][0][r], acc[hs][1][r]),
                            fmaxf(acc[hs][2][r], acc[hs][3][r]));
            m = fmaxf(m, __shfl_xor(m, 1, 64));
            m = fmaxf(m, __shfl_xor(m, 2, 64));
            m = fmaxf(m, __shfl_xor(m, 4, 64));
            m = fmaxf(m, __shfl_xor(m, 8, 64));
            mrow[hs][r] = m;
        }
    if ((lane & 15) == 0) {
        #pragma unroll
        for (int hs = 0; hs < 4; ++hs)
            #pragma unroll
            for (int r = 0; r < 4; ++r)
                redm[w & 1][hbase + hs * 16 + hgrp * 4 + r] = mrow[hs][r];
    }
    __syncthreads();
    #pragma unroll
    for (int hs = 0; hs < 4; ++hs)
        #pragma unroll
        for (int r = 0; r < 4; ++r) {
            const int head = hbase + hs * 16 + hgrp * 4 + r;
            mrow[hs][r] = fmaxf(redm[0][head], redm[1][head]);
        }
    float srow[4][4] = {};
    #pragma unroll
    for (int hs = 0; hs < 4; ++hs)
        #pragma unroll
        for (int ks = 0; ks < 4; ++ks)
            #pragma unroll
            for (int r = 0; r < 4; ++r) {
                const float e = expf(acc[hs][ks][r] - mrow[hs][r]);
                srow[hs][r] += e;
                const int head = hbase + hs * 16 + hgrp * 4 + r;
                const int key  = k0 + kbw + ks * 16 + (lane & 15);
                ph[((size_t)(b * NHEAD + head)) * KVLEN + key] = (_Float16)e;
            }
    #pragma unroll
    for (int hs = 0; hs < 4; ++hs)
        #pragma unroll
        for (int r = 0; r < 4; ++r) {
            float s = srow[hs][r];
            s += __shfl_xor(s, 1, 64);
            s += __shfl_xor(s, 2, 64);
            s += __shfl_xor(s, 4, 64);
            s += __shfl_xor(s, 8, 64);
            srow[hs][r] = s;
        }
    if ((lane & 15) == 0) {
        #pragma unroll
        for (int hs = 0; hs < 4; ++hs)
            #pragma unroll
            for (int r = 0; r < 4; ++r)
                reds[w & 1][hbase + hs * 16 + hgrp * 4 + r] = srow[hs][r];
    }
    __syncthreads();
    if ((w & 1) == 0 && (lane & 15) == 0) {
        #pragma unroll
        for (int hs = 0; hs < 4; ++hs)
            #pragma unroll
            for (int r = 0; r < 4; ++r) {
                const int head = hbase + hs * 16 + hgrp * 4 + r;
                const size_t o = ((size_t)(b * NHEAD + head)) * 64 + blockIdx.x;
                mtab[o] = mrow[hs][r];
                stab[o] = reds[0][head] + reds[1][head];
            }
    }
}

// ---------------- combine: one wave per (b,h) row -----------------------
__global__ __launch_bounds__(256) void softmax_combine(
    const float* __restrict__ mtab, const float* __restrict__ stab,
    float* __restrict__ scales)
{
    const int wv = threadIdx.x >> 6, lane = threadIdx.x & 63;
    const int r = blockIdx.x * 4 + wv;          // b*NHEAD + h
    const float m = mtab[(size_t)r * 64 + lane];
    const float s = stab[(size_t)r * 64 + lane];
    float M = m;
    #pragma unroll
    for (int off = 32; off >= 1; off >>= 1) M = fmaxf(M, __shfl_xor(M, off, 64));
    const float e = expf(m - M);
    float S = s * e;
    #pragma unroll
    for (int off = 32; off >= 1; off >>= 1) S += __shfl_xor(S, off, 64);
    scales[(size_t)r * 64 + lane] = e / S;
}

// ---------------- PV via fp16 MFMA (e*scale x V), dbuf ------------------
// block: 128 heads x 256 l, key-chunk 512; grid (2 l-tiles, 16 ks, 8 b)
// partials written in fp16 (bounded by sum(p)*|V| per chunk)
__global__ __launch_bounds__(256, 1) void pv_mfma(
    const _Float16* __restrict__ ph, const float* __restrict__ scales,
    const float* __restrict__ ckv, _Float16* __restrict__ part)
{
    const int lt = blockIdx.x, ks = blockIdx.y, b = blockIdx.z;
    const int l0 = lt * 256;
    __shared__ __align__(16) _Float16 vbuf[2][256][64];  // chunks 0-3 used, ^(row&7)
    const int tid = threadIdx.x, lane = tid & 63, w = tid >> 6;
    const int hbase = (w >> 1) * 64, lbw = (w & 1) * 128;
    const int lq = (tid & 63) * 4;
    const int kb = (tid >> 6) * 8;
    f32x4 acc[4][8] = {};
    const int kstart = ks * 512;

    float4 v4[8];
    #pragma unroll
    for (int e = 0; e < 8; ++e)
        v4[e] = *reinterpret_cast<const float4*>(
            ckv + ((size_t)(b * KVLEN + kstart + kb + e)) * 512 + l0 + lq);
    f16x8 a[4];
    float sc_h[4];
    #pragma unroll
    for (int hs = 0; hs < 4; ++hs) {
        const int head = hbase + hs * 16 + (lane & 15);
        const size_t poff = ((size_t)(b * NHEAD + head)) * KVLEN
                            + kstart + (lane >> 4) * 8;
        a[hs] = *reinterpret_cast<const f16x8*>(ph + poff);
        sc_h[hs] = scales[((size_t)(b * NHEAD + head)) * 64 + (kstart >> 7)];
    }

    for (int s = 0; s < 16; ++s) {
        const float vv[8][4] = {
            {v4[0].x, v4[0].y, v4[0].z, v4[0].w}, {v4[1].x, v4[1].y, v4[1].z, v4[1].w},
            {v4[2].x, v4[2].y, v4[2].z, v4[2].w}, {v4[3].x, v4[3].y, v4[3].z, v4[3].w},
            {v4[4].x, v4[4].y, v4[4].z, v4[4].w}, {v4[5].x, v4[5].y, v4[5].z, v4[5].w},
            {v4[6].x, v4[6].y, v4[6].z, v4[6].w}, {v4[7].x, v4[7].y, v4[7].z, v4[7].w}};
        #pragma unroll
        for (int j = 0; j < 4; ++j) {
            f16x8 h8;
            #pragma unroll
            for (int e = 0; e < 8; ++e) h8[e] = (_Float16)vv[e][j];
            const int row = lq + j, r7 = row & 7;
            f16x8* rowp = reinterpret_cast<f16x8*>(&vbuf[s & 1][row][0]);
            rowp[(kb >> 3) ^ r7] = h8;
        }
        // scale A-frags (e-values * per-tile scale)
        f16x8 as[4];
        #pragma unroll
        for (int hs = 0; hs < 4; ++hs) {
            const float sc = sc_h[hs];
            #pragma unroll
            for (int e = 0; e < 8; ++e)
                as[hs][e] = (_Float16)((float)a[hs][e] * sc);
        }
        __syncthreads();
        f16x8 na[4];
        float nsc[4];
        if (s + 1 < 16) {
            const int kk = kstart + (s + 1) * 32;
            #pragma unroll
            for (int e = 0; e < 8; ++e)
                v4[e] = *reinterpret_cast<const float4*>(
                    ckv + ((size_t)(b * KVLEN + kk + kb + e)) * 512 + l0 + lq);
            #pragma unroll
            for (int hs = 0; hs < 4; ++hs) {
                const int head = hbase + hs * 16 + (lane & 15);
                const size_t poff = ((size_t)(b * NHEAD + head)) * KVLEN
                                    + kk + (lane >> 4) * 8;
                na[hs] = *reinterpret_cast<const f16x8*>(ph + poff);
                nsc[hs] = scales[((size_t)(b * NHEAD + head)) * 64 + (kk >> 7)];
            }
        }
        #pragma unroll
        for (int ls = 0; ls < 8; ++ls) {
            const int row = lbw + ls * 16 + (lane & 15);
            const f16x8* rp = reinterpret_cast<const f16x8*>(&vbuf[s & 1][row][0]);
            const int r7 = row & 7;
            const f16x8 vf = rp[(lane >> 4) ^ r7];
            #pragma unroll
            for (int hs = 0; hs < 4; ++hs)
                acc[hs][ls] = __builtin_amdgcn_mfma_f32_16x16x32_f16(as[hs], vf, acc[hs][ls], 0, 0, 0);
        }
        if (s + 1 < 16) {
            #pragma unroll
            for (int hs = 0; hs < 4; ++hs) { a[hs] = na[hs]; sc_h[hs] = nsc[hs]; }
        }
    }
    #pragma unroll
    for (int hs = 0; hs < 4; ++hs)
        #pragma unroll
        for (int ls = 0; ls < 8; ++ls)
            #pragma unroll
            for (int r = 0; r < 4; ++r) {
                const int head = hbase + hs * 16 + (lane >> 4) * 4 + r;
                const int l    = l0 + lbw + ls * 16 + (lane & 15);
                part[(((size_t)ks * B_SZ + b) * NHEAD + head) * KVLR_D + l]
                    = (_Float16)acc[hs][ls][r];
            }
}

// ---------------- attn reduce (16 fp16 splits, f16x4 loads) -------------
__global__ __launch_bounds__(256) void reduce_attn(
    const _Float16* __restrict__ part, float* __restrict__ attn)
{
    const int t = blockIdx.x * 256 + threadIdx.x;
    const size_t i4 = (size_t)t * 4;
    if (i4 >= (size_t)524288) return;
    float4 acc = make_float4(0.f, 0.f, 0.f, 0.f);
    #pragma unroll
    for (int s = 0; s < 16; ++s) {
        const f16x4 v = *reinterpret_cast<const f16x4*>(part + (size_t)s * 524288 + i4);
        acc.x += (float)v[0]; acc.y += (float)v[1];
        acc.z += (float)v[2]; acc.w += (float)v[3];
    }
    *reinterpret_cast<float4*>(attn + i4) = acc;
}

// ---------------- final output reduce, two stages -----------------------
__global__ __launch_bounds__(256) void final_r1(
    const float* __restrict__ part, float* __restrict__ part2)
{
    const int t = blockIdx.x * 256 + threadIdx.x;   // 10240 threads
    const size_t i4 = (size_t)t * 4;
    const int sg = blockIdx.y;
    float4 acc = make_float4(0.f, 0.f, 0.f, 0.f);
    #pragma unroll 8
    for (int s = 0; s < 32; ++s) {
        const float4 v = *reinterpret_cast<const float4*>(
            part + ((size_t)(sg * 32 + s)) * 40960 + i4);
        acc.x += v.x; acc.y += v.y; acc.z += v.z; acc.w += v.w;
    }
    *reinterpret_cast<float4*>(part2 + (size_t)sg * 40960 + i4) = acc;
}

__global__ __launch_bounds__(256) void final_r2(
    const float* __restrict__ part2, float* __restrict__ out)
{
    const int t = blockIdx.x * 256 + threadIdx.x;
    const size_t i4 = (size_t)t * 4;
    float4 acc = make_float4(0.f, 0.f, 0.f, 0.f);
    #pragma unroll
    for (int s = 0; s < 4; ++s) {
        const float4 v = *reinterpret_cast<const float4*>(part2 + (size_t)s * 40960 + i4);
        acc.x += v.x; acc.y += v.y; acc.z += v.z; acc.w += v.w;
    }
    *reinterpret_cast<float4*>(out + i4) = acc;
}

extern "C" void kernel_launch(void* const* d_in, const int* in_sizes, int n_in,
                              void* d_out, int out_size, void* d_ws, size_t ws_size,
                              hipStream_t stream)
{
    const float* hidden  = (const float*)d_in[0];
    const float* ckv     = (const float*)d_in[1];
    const float* kpe     = (const float*)d_in[2];
    const float* W_DQ    = (const float*)d_in[3];
    const float* ln_w    = (const float*)d_in[4];
    const float* W_QR    = (const float*)d_in[5];
    const float* W_UQ_UK = (const float*)d_in[6];
    const float* W_UV_O  = (const float*)d_in[7];
    float* out = (float*)d_out;
    float* ws  = (float*)d_ws;

    float* cqy    = ws + WS_CQY;
    float* ssp    = ws + WS_SSP;
    float* cq     = ws + WS_CQ;
    float2* trig  = (float2*)(ws + WS_TRIG);
    _Float16* qh  = (_Float16*)(ws + WS_QH);
    _Float16* prh = (_Float16*)(ws + WS_PH);
    float* mtab   = ws + WS_MT;
    float* stab   = ws + WS_ST;
    float* scales = ws + WS_SC;
    float* attn   = ws + WS_ATTN;
    float* part   = ws + WS_PART;
    _Float16* partH = (_Float16*)(ws + WS_PART);
    float* part2  = ws + WS_PART2;

    // trig table first (independent)
    trig_table_kernel<<<1024, 256, 0, stream>>>(trig);
    // 1. cQ = rmsnorm(hidden @ W_DQ)
    gemv8_splitk<<<dim3(2, 80), 256, 0, stream>>>(hidden, W_DQ, part, H_DIM, QLR_D, 64);
    rms_stageA<<<dim3(6, 8), 256, 0, stream>>>(part, cqy, ssp, 80);
    rms_stageB<<<8, 256, 0, stream>>>(cqy, ssp, ln_w, cq);
    // 2. q_pe = rope(cQ @ W_QR) -> qh[0:64]
    gemv8_splitk<<<dim3(8, 32), 256, 0, stream>>>(cq, W_QR, part, QLR_D, NHEAD * ROPE_D, 48);
    reduce_rope_q<<<128, 256, 0, stream>>>(part, qh, 32);
    // 3. q_nope = cQ @ W_UQ_UK -> qh[64:576]  (8 splits, 512 blocks)
    gemv8_splitk<<<dim3(64, 8), 256, 0, stream>>>(cq, W_UQ_UK, part, QLR_D, NHEAD * KVLR_D, 192);
    reduce_convert_q<<<512, 256, 0, stream>>>(part, qh);
    // 4. scores + tile-softmax (fused k_pe RoPE) -> fp16 e-values + m/s tables
    scores_mfma<<<dim3(64, 8), 256, 0, stream>>>(qh, kpe, ckv, trig, prh, mtab, stab);
    // 5. combine -> per-tile scales (wave-parallel)
    softmax_combine<<<256, 256, 0, stream>>>(mtab, stab, scales);
    // 6. attn = (e*scale) @ ckv (split-K 16, 2 l-tiles), fp16 partials
    pv_mfma<<<dim3(2, 16, 8), 256, 0, stream>>>(prh, scales, ckv, partH);
    reduce_attn<<<512, 256, 0, stream>>>(partH, attn);
    // 7. out = attn @ W_UV_O (128 splits)
    gemv8_splitk<<<dim3(5, 128), 256, 0, stream>>>(attn, W_UV_O, part, NHEAD * KVLR_D, H_DIM, 512);
    final_r1<<<dim3(40, 4), 256, 0, stream>>>(part, part2);
    final_r2<<<40, 256, 0, stream>>>(part2, out);
}